// Round 4
// baseline (794.756 us; speedup 1.0000x reference)
//
#include <hip/hip_runtime.h>
#include <hip/hip_bf16.h>

#define S_LEN 4096
#define HIDDEN 1024
#define NH 8
#define NKV 2
#define HD 128
#define WIN 2048
#define GROUPS (NH / NKV)   // 4 query heads per kv head

typedef short bf16x8 __attribute__((ext_vector_type(8)));
typedef float f32x4 __attribute__((ext_vector_type(4)));

__device__ __forceinline__ unsigned short f2b(float f) {
    unsigned int u = __builtin_bit_cast(unsigned int, f);
    u += 0x7fffu + ((u >> 16) & 1u);     // round-to-nearest-even
    return (unsigned short)(u >> 16);
}

// 8-element bf16 fragment loader, overloaded on source dtype.
__device__ __forceinline__ bf16x8 ld8(const unsigned short* p) {
    return *(const bf16x8*)p;
}
__device__ __forceinline__ bf16x8 ld8(const float* p) {
    f32x4 a = *(const f32x4*)p;
    f32x4 b = *(const f32x4*)(p + 4);
    bf16x8 r;
    r[0] = (short)f2b(a[0]); r[1] = (short)f2b(a[1]);
    r[2] = (short)f2b(a[2]); r[3] = (short)f2b(a[3]);
    r[4] = (short)f2b(b[0]); r[5] = (short)f2b(b[1]);
    r[6] = (short)f2b(b[2]); r[7] = (short)f2b(b[3]);
    return r;
}

// ---------------------------------------------------------------------------
// Float dtype sniffing (insurance; evidence says fp32): bf16 buffers have
// sane exponent fields in every short; fp32 buffers have mantissa junk in
// every low short.  flag=1 -> bf16 inputs; flag=0 -> fp32 inputs.
// ---------------------------------------------------------------------------
__global__ void detect_dtype(const unsigned short* __restrict__ hidden,
                             int* __restrict__ flag)
{
    int lane = threadIdx.x;                 // 64 threads, 1 block
    unsigned short s = hidden[lane];
    int e = (s >> 7) & 0xFF;                // bf16 exponent field
    int plaus = (e == 0 || (e >= 110 && e <= 140)) ? 1 : 0;
    unsigned long long m = __ballot(plaus);
    if (lane == 0) *flag = (__popcll(m) >= 56) ? 1 : 0;
}

// ---------------------------------------------------------------------------
// C = A @ W^T.  A: MxK row-major (dtype TA).  W: NxK row-major (dtype TW).
// Each wave computes a 16x64 tile: 4 accumulators, A-frag reused 4x.
// Writes fp32 (Cf) or bf16 (Cb).  Runs only when *flag == want.
// ---------------------------------------------------------------------------
template <typename TA, typename TW>
__global__ __launch_bounds__(256) void gemm_bt(
    const int* __restrict__ flag, int want,
    const TA* __restrict__ A, const TW* __restrict__ W,
    float* __restrict__ Cf, unsigned short* __restrict__ Cb,
    int M, int N, int K)
{
    if (*flag != want) return;

    int lane = threadIdx.x & 63;
    int l15 = lane & 15, quad = lane >> 4;
    int wid = (int)((blockIdx.x * 256u + threadIdx.x) >> 6);
    int tiles_n = N >> 6;
    int mt = wid / tiles_n;
    int nt = wid - mt * tiles_n;

    const TA* arow = A + (size_t)(mt * 16 + l15) * K + quad * 8;
    const TW* wrow = W + (size_t)(nt * 64 + l15) * K + quad * 8;

    f32x4 acc[4];
    #pragma unroll
    for (int j = 0; j < 4; ++j) acc[j] = (f32x4){0.f, 0.f, 0.f, 0.f};

    for (int k0 = 0; k0 < K; k0 += 32) {
        bf16x8 a = ld8(arow + k0);
        #pragma unroll
        for (int j = 0; j < 4; ++j) {
            bf16x8 b = ld8(wrow + (size_t)j * 16 * K + k0);
            acc[j] = __builtin_amdgcn_mfma_f32_16x16x32_bf16(a, b, acc[j], 0, 0, 0);
        }
    }

    int row0 = mt * 16 + quad * 4;
    int col0 = nt * 64 + l15;
    if (Cf) {
        #pragma unroll
        for (int reg = 0; reg < 4; ++reg) {
            size_t r = (size_t)(row0 + reg) * N + col0;
            #pragma unroll
            for (int j = 0; j < 4; ++j) Cf[r + j * 16] = acc[j][reg];
        }
    } else {
        #pragma unroll
        for (int reg = 0; reg < 4; ++reg) {
            size_t r = (size_t)(row0 + reg) * N + col0;
            #pragma unroll
            for (int j = 0; j < 4; ++j) Cb[r + j * 16] = f2b(acc[j][reg]);
        }
    }
}

// ---------------------------------------------------------------------------
// RoPE on Q,K (fp32 in -> bf16 out) + V convert to bf16 TRANSPOSED Vt[d][s].
// 12 "slots" per position: 8 Q heads, 2 K heads (rotated), 2 V heads (copy).
// Thread handles the (d, d+64) rotation pair, d in [0,64).
// position_ids sniffed int32 vs int64 (int64 arange has zero high words).
// ---------------------------------------------------------------------------
__global__ __launch_bounds__(256) void rope_convert(
    const float* __restrict__ Qf, const float* __restrict__ Kf,
    const float* __restrict__ Vf, const int* __restrict__ pos,
    unsigned short* __restrict__ Qb, unsigned short* __restrict__ Kb,
    unsigned short* __restrict__ Vt)
{
    int tid = blockIdx.x * 256 + threadIdx.x;
    int s = tid / (12 * 64);
    int r = tid - s * (12 * 64);
    int slot = r >> 6;
    int d = r & 63;
    if (s >= S_LEN) return;

    if (slot < 10) {
        bool is64 = (pos[1] == 0) && (pos[3] == 0);
        int pv = is64 ? pos[2 * s] : pos[s];
        float p = (float)pv;
        // inv_freq = 10000^(-d/64) = 2^(-d * log2(10000)/64)
        float inv = exp2f(-(float)d * (13.287712379549449f / 64.0f));
        float ang = p * inv;
        float c = cosf(ang), sn = sinf(ang);
        if (slot < 8) {
            size_t base = (size_t)s * HIDDEN + slot * HD + d;
            float x1 = Qf[base], x2 = Qf[base + 64];
            Qb[base]      = f2b(x1 * c - x2 * sn);
            Qb[base + 64] = f2b(x2 * c + x1 * sn);
        } else {
            int kvh = slot - 8;
            size_t base = (size_t)s * (NKV * HD) + kvh * HD + d;
            float x1 = Kf[base], x2 = Kf[base + 64];
            Kb[base]      = f2b(x1 * c - x2 * sn);
            Kb[base + 64] = f2b(x2 * c + x1 * sn);
        }
    } else {
        int kvh = slot - 10;
        size_t base = (size_t)s * (NKV * HD) + kvh * HD + d;
        Vt[(size_t)(kvh * HD + d) * S_LEN + s]      = f2b(Vf[base]);
        Vt[(size_t)(kvh * HD + d + 64) * S_LEN + s] = f2b(Vf[base + 64]);
    }
}

// ---------------------------------------------------------------------------
// Sliding-window causal flash attention, GQA 8q/2kv, D=128, window 2048.
// Block = 4 waves = 64 queries of one head; each wave owns 16 queries.
// 32-key chunks; uniform per-block loop bounds so __syncthreads is legal.
// Softmax state (m,l) lives in C-layout registers (row = quad*4+reg,
// replicated across the 16 lanes of each quad).  P goes through LDS to
// convert C-layout -> A-layout (stride 48 shorts: 16B-aligned b128 reads).
// ---------------------------------------------------------------------------
#define PSTR 48
__global__ __launch_bounds__(256) void attn_fwd(
    const unsigned short* __restrict__ Qb, const unsigned short* __restrict__ Kb,
    const unsigned short* __restrict__ Vt, unsigned short* __restrict__ Ctx)
{
    __shared__ alignas(16) unsigned short P_lds[4][16 * PSTR];

    int lane = threadIdx.x & 63;
    int w = threadIdx.x >> 6;
    int l15 = lane & 15, quad = lane >> 4;
    int h = blockIdx.y;
    int kv = h / GROUPS;
    int qb_block = blockIdx.x * 64;
    int qb = qb_block + w * 16;

    // Q fragments (A-layout): lane = query l15, k = quad*8.. ; 4 d-steps of 32
    bf16x8 a_q[4];
    const unsigned short* qrow = Qb + (size_t)(qb + l15) * HIDDEN + h * HD + quad * 8;
    #pragma unroll
    for (int st = 0; st < 4; ++st) a_q[st] = *(const bf16x8*)(qrow + st * 32);

    f32x4 o[8];
    #pragma unroll
    for (int nd = 0; nd < 8; ++nd) o[nd] = (f32x4){0.f, 0.f, 0.f, 0.f};
    float m_s[4] = {-1e30f, -1e30f, -1e30f, -1e30f};
    float l_s[4] = {0.f, 0.f, 0.f, 0.f};

    int j_lo = qb_block - (WIN - 1);
    if (j_lo < 0) j_lo = 0;
    j_lo &= ~31;

    const unsigned short* vbase = Vt + (size_t)kv * HD * S_LEN;
    const float scale = 0.08838834764831843f;   // 1/sqrt(128)

    for (int j0 = j_lo; j0 < qb_block + 64; j0 += 32) {
        // ---- scores: S[16q][32k] as two 16x16 MFMA tiles
        f32x4 s0 = (f32x4){0.f, 0.f, 0.f, 0.f};
        f32x4 s1 = (f32x4){0.f, 0.f, 0.f, 0.f};
        const unsigned short* k0p = Kb + (size_t)(j0 + l15) * (NKV * HD) + kv * HD + quad * 8;
        const unsigned short* k1p = k0p + (size_t)16 * (NKV * HD);
        #pragma unroll
        for (int st = 0; st < 4; ++st) {
            bf16x8 b0 = *(const bf16x8*)(k0p + st * 32);
            bf16x8 b1 = *(const bf16x8*)(k1p + st * 32);
            s0 = __builtin_amdgcn_mfma_f32_16x16x32_bf16(a_q[st], b0, s0, 0, 0, 0);
            s1 = __builtin_amdgcn_mfma_f32_16x16x32_bf16(a_q[st], b1, s1, 0, 0, 0);
        }

        // ---- mask + online softmax (per C-layout row = quad*4+reg)
        float p0[4], p1[4], alpha[4];
        int jj0 = j0 + l15, jj1 = j0 + 16 + l15;
        #pragma unroll
        for (int reg = 0; reg < 4; ++reg) {
            int i = qb + quad * 4 + reg;
            float v0 = (jj0 <= i && jj0 > i - WIN) ? s0[reg] * scale : -1e30f;
            float v1 = (jj1 <= i && jj1 > i - WIN) ? s1[reg] * scale : -1e30f;
            float t = fmaxf(v0, v1);
            t = fmaxf(t, __shfl_xor(t, 1, 64));
            t = fmaxf(t, __shfl_xor(t, 2, 64));
            t = fmaxf(t, __shfl_xor(t, 4, 64));
            t = fmaxf(t, __shfl_xor(t, 8, 64));
            float mn = fmaxf(m_s[reg], t);
            alpha[reg] = __expf(m_s[reg] - mn);   // ==1 while mn==-1e30 (garbage zeroed by later alpha=0)
            m_s[reg] = mn;
            float e0 = __expf(v0 - mn);
            float e1 = __expf(v1 - mn);
            p0[reg] = e0; p1[reg] = e1;
            float rs = e0 + e1;
            rs += __shfl_xor(rs, 1, 64);
            rs += __shfl_xor(rs, 2, 64);
            rs += __shfl_xor(rs, 4, 64);
            rs += __shfl_xor(rs, 8, 64);
            l_s[reg] = l_s[reg] * alpha[reg] + rs;
        }

        // ---- write P (bf16) to per-wave LDS region, C-layout positions
        unsigned short* pw = &P_lds[w][0];
        #pragma unroll
        for (int reg = 0; reg < 4; ++reg) {
            int row = quad * 4 + reg;
            pw[row * PSTR + l15]      = f2b(p0[reg]);
            pw[row * PSTR + 16 + l15] = f2b(p1[reg]);
        }

        // ---- rescale O accumulators by alpha (same row mapping for all tiles)
        #pragma unroll
        for (int nd = 0; nd < 8; ++nd)
            #pragma unroll
            for (int reg = 0; reg < 4; ++reg) o[nd][reg] *= alpha[reg];

        __syncthreads();   // LDS fence before cross-layout read

        // ---- P in A-layout: lane = query l15, k = key_local quad*8..+7
        bf16x8 a_p = *(const bf16x8*)(pw + l15 * PSTR + quad * 8);

        // ---- O += P @ V  (V fragments direct from transposed global Vt[d][s])
        const unsigned short* vrow = vbase + (size_t)l15 * S_LEN + j0 + quad * 8;
        #pragma unroll
        for (int nd = 0; nd < 8; ++nd) {
            bf16x8 b_v = *(const bf16x8*)(vrow + (size_t)nd * 16 * S_LEN);
            o[nd] = __builtin_amdgcn_mfma_f32_16x16x32_bf16(a_p, b_v, o[nd], 0, 0, 0);
        }
        __syncthreads();   // P region reusable next chunk
    }

    // ---- epilogue: ctx[s][h*128+d] = o/l
    #pragma unroll
    for (int nd = 0; nd < 8; ++nd) {
        int d = nd * 16 + l15;
        #pragma unroll
        for (int reg = 0; reg < 4; ++reg) {
            int q = qb + quad * 4 + reg;
            Ctx[(size_t)q * HIDDEN + h * HD + d] = f2b(o[nd][reg] / l_s[reg]);
        }
    }
}

// ---------------------------------------------------------------------------
extern "C" void kernel_launch(void* const* d_in, const int* in_sizes, int n_in,
                              void* d_out, int out_size, void* d_ws, size_t ws_size,
                              hipStream_t stream)
{
    const void* hidden = d_in[0];
    const void* wq = d_in[1];
    const void* wk = d_in[2];
    const void* wv = d_in[3];
    const void* wo = d_in[4];
    const int* pos = (const int*)d_in[5];
    float* out = (float*)d_out;          // reference output dtype: float32

    char* ws = (char*)d_ws;
    int* flag = (int*)ws;
    size_t off = 256;
    float* Qf = (float*)(ws + off); off += (size_t)S_LEN * HIDDEN * 4;       // 16.8 MB
    float* Kf = (float*)(ws + off); off += (size_t)S_LEN * NKV * HD * 4;     //  4.2 MB
    float* Vf = (float*)(ws + off); off += (size_t)S_LEN * NKV * HD * 4;     //  4.2 MB
    unsigned short* Qb = (unsigned short*)(ws + off); off += (size_t)S_LEN * HIDDEN * 2;
    unsigned short* Kb = (unsigned short*)(ws + off); off += (size_t)S_LEN * NKV * HD * 2;
    unsigned short* Vt = (unsigned short*)(ws + off); off += (size_t)S_LEN * NKV * HD * 2;
    unsigned short* Cb = (unsigned short*)(ws + off); off += (size_t)S_LEN * HIDDEN * 2;
    // total ~46 MB

    detect_dtype<<<1, 64, 0, stream>>>((const unsigned short*)hidden, flag);

    const int QGRID = (S_LEN / 16) * (HIDDEN / 64) / 4;
    const int KVGRID = (S_LEN / 16) * ((NKV * HD) / 64) / 4;

    // Q/K/V projections (fp32 out) — both dtype paths launched, flag-gated.
    gemm_bt<unsigned short, unsigned short><<<QGRID, 256, 0, stream>>>(
        flag, 1, (const unsigned short*)hidden, (const unsigned short*)wq,
        Qf, nullptr, S_LEN, HIDDEN, HIDDEN);
    gemm_bt<float, float><<<QGRID, 256, 0, stream>>>(
        flag, 0, (const float*)hidden, (const float*)wq,
        Qf, nullptr, S_LEN, HIDDEN, HIDDEN);

    gemm_bt<unsigned short, unsigned short><<<KVGRID, 256, 0, stream>>>(
        flag, 1, (const unsigned short*)hidden, (const unsigned short*)wk,
        Kf, nullptr, S_LEN, NKV * HD, HIDDEN);
    gemm_bt<float, float><<<KVGRID, 256, 0, stream>>>(
        flag, 0, (const float*)hidden, (const float*)wk,
        Kf, nullptr, S_LEN, NKV * HD, HIDDEN);

    gemm_bt<unsigned short, unsigned short><<<KVGRID, 256, 0, stream>>>(
        flag, 1, (const unsigned short*)hidden, (const unsigned short*)wv,
        Vf, nullptr, S_LEN, NKV * HD, HIDDEN);
    gemm_bt<float, float><<<KVGRID, 256, 0, stream>>>(
        flag, 0, (const float*)hidden, (const float*)wv,
        Vf, nullptr, S_LEN, NKV * HD, HIDDEN);

    // RoPE + bf16 convert (+ V transpose) — ws is always fp32 here
    rope_convert<<<dim3(S_LEN * 12 * 64 / 256), 256, 0, stream>>>(
        Qf, Kf, Vf, pos, Qb, Kb, Vt);

    // flash attention — ws bf16 always
    attn_fwd<<<dim3(S_LEN / 64, NH), 256, 0, stream>>>(Qb, Kb, Vt, Cb);

    // output projection -> FLOAT32 d_out (A is always bf16 ws; W flag-gated)
    gemm_bt<unsigned short, unsigned short><<<QGRID, 256, 0, stream>>>(
        flag, 1, Cb, (const unsigned short*)wo, out, nullptr, S_LEN, HIDDEN, HIDDEN);
    gemm_bt<unsigned short, float><<<QGRID, 256, 0, stream>>>(
        flag, 0, Cb, (const float*)wo, out, nullptr, S_LEN, HIDDEN, HIDDEN);
}

// Round 5
// 455.749 us; speedup vs baseline: 1.7438x; 1.7438x over previous
//
#include <hip/hip_runtime.h>

#define S_LEN 4096
#define HIDDEN 1024
#define NH 8
#define NKV 2
#define HD 128
#define WIN 2048

typedef short bf16x8 __attribute__((ext_vector_type(8)));
typedef float f32x4 __attribute__((ext_vector_type(4)));
typedef unsigned short u16x4 __attribute__((ext_vector_type(4)));

__device__ __forceinline__ unsigned short f2b(float f) {
    unsigned int u = __builtin_bit_cast(unsigned int, f);
    u += 0x7fffu + ((u >> 16) & 1u);     // round-to-nearest-even
    return (unsigned short)(u >> 16);
}
__device__ __forceinline__ float b2f(unsigned short u) {
    unsigned int x = ((unsigned int)u) << 16;
    return __builtin_bit_cast(float, x);
}

// ---------------------------------------------------------------------------
// One-shot fp32 -> bf16 of the five input tensors (float4 granularity).
// ---------------------------------------------------------------------------
__global__ __launch_bounds__(256) void cvt5(
    const float* __restrict__ s0, unsigned short* __restrict__ t0, int n0,
    const float* __restrict__ s1, unsigned short* __restrict__ t1, int n1,
    const float* __restrict__ s2, unsigned short* __restrict__ t2, int n2,
    const float* __restrict__ s3, unsigned short* __restrict__ t3, int n3,
    const float* __restrict__ s4, unsigned short* __restrict__ t4, int n4)
{
    int i = blockIdx.x * 256 + threadIdx.x;   // float4 index
    const float* s; unsigned short* t;
    if (i < n0)              { s = s0; t = t0; }
    else if ((i -= n0) < n1) { s = s1; t = t1; }
    else if ((i -= n1) < n2) { s = s2; t = t2; }
    else if ((i -= n2) < n3) { s = s3; t = t3; }
    else if ((i -= n3) < n4) { s = s4; t = t4; }
    else return;
    f32x4 v = *(const f32x4*)(s + (size_t)i * 4);
    u16x4 r = { f2b(v[0]), f2b(v[1]), f2b(v[2]), f2b(v[3]) };
    *(u16x4*)(t + (size_t)i * 4) = r;
}

// ---------------------------------------------------------------------------
// C = A @ W^T, all bf16 in.  A: MxK row-major.  W: NxK row-major.
// Wave tile 32x64: 2 A-frags x 4 W-frags = 8 independent MFMAs per K-step.
// Writes fp32 (Cf) or bf16 (Cb).
// ---------------------------------------------------------------------------
__global__ __launch_bounds__(256) void gemm32(
    const unsigned short* __restrict__ A, const unsigned short* __restrict__ W,
    float* __restrict__ Cf, unsigned short* __restrict__ Cb,
    int M, int N, int K)
{
    int lane = threadIdx.x & 63;
    int l15 = lane & 15, quad = lane >> 4;
    int wid = (int)((blockIdx.x * 256u + threadIdx.x) >> 6);
    int tiles_n = N >> 6;
    int mt = wid / tiles_n;
    int nt = wid - mt * tiles_n;

    const unsigned short* arow0 = A + (size_t)(mt * 32 + l15) * K + quad * 8;
    const unsigned short* arow1 = arow0 + (size_t)16 * K;
    const unsigned short* wrow  = W + (size_t)(nt * 64 + l15) * K + quad * 8;

    f32x4 acc[2][4];
    #pragma unroll
    for (int i = 0; i < 2; ++i)
        #pragma unroll
        for (int j = 0; j < 4; ++j) acc[i][j] = (f32x4){0.f, 0.f, 0.f, 0.f};

    for (int k0 = 0; k0 < K; k0 += 32) {
        bf16x8 a0 = *(const bf16x8*)(arow0 + k0);
        bf16x8 a1 = *(const bf16x8*)(arow1 + k0);
        #pragma unroll
        for (int j = 0; j < 4; ++j) {
            bf16x8 b = *(const bf16x8*)(wrow + (size_t)j * 16 * K + k0);
            acc[0][j] = __builtin_amdgcn_mfma_f32_16x16x32_bf16(a0, b, acc[0][j], 0, 0, 0);
            acc[1][j] = __builtin_amdgcn_mfma_f32_16x16x32_bf16(a1, b, acc[1][j], 0, 0, 0);
        }
    }

    #pragma unroll
    for (int i = 0; i < 2; ++i) {
        int row0 = mt * 32 + i * 16 + quad * 4;
        int col0 = nt * 64 + l15;
        if (Cf) {
            #pragma unroll
            for (int reg = 0; reg < 4; ++reg) {
                size_t r = (size_t)(row0 + reg) * N + col0;
                #pragma unroll
                for (int j = 0; j < 4; ++j) Cf[r + j * 16] = acc[i][j][reg];
            }
        } else {
            #pragma unroll
            for (int reg = 0; reg < 4; ++reg) {
                size_t r = (size_t)(row0 + reg) * N + col0;
                #pragma unroll
                for (int j = 0; j < 4; ++j) Cb[r + j * 16] = f2b(acc[i][j][reg]);
            }
        }
    }
}

// ---------------------------------------------------------------------------
// RoPE on Q,K (bf16 in -> bf16 out) + V copy to bf16 TRANSPOSED Vt[d][s].
// position_ids sniffed int32 vs int64 (int64 arange has zero high words).
// ---------------------------------------------------------------------------
__global__ __launch_bounds__(256) void rope_convert(
    const unsigned short* __restrict__ Qg, const unsigned short* __restrict__ Kg,
    const unsigned short* __restrict__ Vg, const int* __restrict__ pos,
    unsigned short* __restrict__ Qb, unsigned short* __restrict__ Kb,
    unsigned short* __restrict__ Vt)
{
    int tid = blockIdx.x * 256 + threadIdx.x;
    int s = tid / (12 * 64);
    int r = tid - s * (12 * 64);
    int slot = r >> 6;
    int d = r & 63;
    if (s >= S_LEN) return;

    if (slot < 10) {
        bool is64 = (pos[1] == 0) && (pos[3] == 0);
        int pv = is64 ? pos[2 * s] : pos[s];
        float p = (float)pv;
        float inv = exp2f(-(float)d * (13.287712379549449f / 64.0f));
        float ang = p * inv;
        float c = cosf(ang), sn = sinf(ang);
        if (slot < 8) {
            size_t base = (size_t)s * HIDDEN + slot * HD + d;
            float x1 = b2f(Qg[base]), x2 = b2f(Qg[base + 64]);
            Qb[base]      = f2b(x1 * c - x2 * sn);
            Qb[base + 64] = f2b(x2 * c + x1 * sn);
        } else {
            int kvh = slot - 8;
            size_t base = (size_t)s * (NKV * HD) + kvh * HD + d;
            float x1 = b2f(Kg[base]), x2 = b2f(Kg[base + 64]);
            Kb[base]      = f2b(x1 * c - x2 * sn);
            Kb[base + 64] = f2b(x2 * c + x1 * sn);
        }
    } else {
        int kvh = slot - 10;
        size_t base = (size_t)s * (NKV * HD) + kvh * HD + d;
        Vt[(size_t)(kvh * HD + d) * S_LEN + s]      = Vg[base];
        Vt[(size_t)(kvh * HD + d + 64) * S_LEN + s] = Vg[base + 64];
    }
}

// ---------------------------------------------------------------------------
// Split-K sliding-window flash attention.  Block = 16 queries of one head;
// the 4 waves each take ~1/4 of the key window (independent online softmax),
// then partials merge through LDS.  No block barrier inside the key loop:
// the P C-layout->A-layout round-trip uses WAVE-PRIVATE LDS ordered by an
// explicit s_waitcnt lgkmcnt(0) (wave-synchronous idiom).
// Invalid partials (fully-masked range: m stays -1e30) get merge weight 0.
// ---------------------------------------------------------------------------
#define PSTR 48
#define OSTR 136
__global__ __launch_bounds__(256) void attn_split(
    const unsigned short* __restrict__ Qb, const unsigned short* __restrict__ Kb,
    const unsigned short* __restrict__ Vt, unsigned short* __restrict__ Ctx)
{
    __shared__ alignas(16) unsigned short P_lds[4][16 * PSTR];   //  6 KB
    __shared__ alignas(16) unsigned short O_lds[4][16 * OSTR];   // 17 KB (bf16, padded)
    __shared__ float m_lds[4][16];
    __shared__ float l_lds[4][16];

    int lane = threadIdx.x & 63;
    int w = threadIdx.x >> 6;
    int l15 = lane & 15, quad = lane >> 4;
    int qt = blockIdx.x;
    int h = blockIdx.y;
    int kv = h >> 2;                 // GROUPS = 4
    int qb = qt * 16;

    // Q fragments (A-layout): lane = query l15, k = quad*8.. ; 4 d-steps of 32
    bf16x8 a_q[4];
    const unsigned short* qrow = Qb + (size_t)(qb + l15) * HIDDEN + h * HD + quad * 8;
    #pragma unroll
    for (int st = 0; st < 4; ++st) a_q[st] = *(const bf16x8*)(qrow + st * 32);

    // key-range split: chunks of 32 keys
    int hi = qb + 16;
    int lo = qb + 15 - (WIN - 1); if (lo < 0) lo = 0; lo &= ~31;
    int nch = (hi - lo + 31) >> 5;
    int per = (nch + 3) >> 2;
    int c0 = w * per;
    int c1 = nch < c0 + per ? nch : c0 + per;

    f32x4 o[8];
    #pragma unroll
    for (int nd = 0; nd < 8; ++nd) o[nd] = (f32x4){0.f, 0.f, 0.f, 0.f};
    float m_s[4] = {-1e30f, -1e30f, -1e30f, -1e30f};
    float l_s[4] = {0.f, 0.f, 0.f, 0.f};

    const unsigned short* vbase = Vt + (size_t)kv * HD * S_LEN;
    unsigned short* pw = &P_lds[w][0];
    const float scale = 0.08838834764831843f;   // 1/sqrt(128)

    for (int c = c0; c < c1; ++c) {
        int j0 = lo + c * 32;

        // ---- scores: S[16q][32k] as two 16x16 MFMA tiles
        f32x4 s0 = (f32x4){0.f, 0.f, 0.f, 0.f};
        f32x4 s1 = (f32x4){0.f, 0.f, 0.f, 0.f};
        const unsigned short* k0p = Kb + (size_t)(j0 + l15) * (NKV * HD) + kv * HD + quad * 8;
        const unsigned short* k1p = k0p + (size_t)16 * (NKV * HD);
        #pragma unroll
        for (int st = 0; st < 4; ++st) {
            bf16x8 b0 = *(const bf16x8*)(k0p + st * 32);
            bf16x8 b1 = *(const bf16x8*)(k1p + st * 32);
            s0 = __builtin_amdgcn_mfma_f32_16x16x32_bf16(a_q[st], b0, s0, 0, 0, 0);
            s1 = __builtin_amdgcn_mfma_f32_16x16x32_bf16(a_q[st], b1, s1, 0, 0, 0);
        }

        // ---- mask + online softmax (per C-layout row = quad*4+reg)
        float p0[4], p1[4], alpha[4];
        int jj0 = j0 + l15, jj1 = j0 + 16 + l15;
        #pragma unroll
        for (int reg = 0; reg < 4; ++reg) {
            int i = qb + quad * 4 + reg;
            float v0 = (jj0 <= i && jj0 > i - WIN) ? s0[reg] * scale : -1e30f;
            float v1 = (jj1 <= i && jj1 > i - WIN) ? s1[reg] * scale : -1e30f;
            float t = fmaxf(v0, v1);
            t = fmaxf(t, __shfl_xor(t, 1, 64));
            t = fmaxf(t, __shfl_xor(t, 2, 64));
            t = fmaxf(t, __shfl_xor(t, 4, 64));
            t = fmaxf(t, __shfl_xor(t, 8, 64));
            float mn = fmaxf(m_s[reg], t);
            alpha[reg] = __expf(m_s[reg] - mn);   // garbage from all-masked prefix zeroed here
            m_s[reg] = mn;
            float e0 = __expf(v0 - mn);
            float e1 = __expf(v1 - mn);
            p0[reg] = e0; p1[reg] = e1;
            float rs = e0 + e1;
            rs += __shfl_xor(rs, 1, 64);
            rs += __shfl_xor(rs, 2, 64);
            rs += __shfl_xor(rs, 4, 64);
            rs += __shfl_xor(rs, 8, 64);
            l_s[reg] = l_s[reg] * alpha[reg] + rs;
        }

        // ---- write P (bf16) to wave-private LDS, C-layout positions
        #pragma unroll
        for (int reg = 0; reg < 4; ++reg) {
            int row = quad * 4 + reg;
            pw[row * PSTR + l15]      = f2b(p0[reg]);
            pw[row * PSTR + 16 + l15] = f2b(p1[reg]);
        }

        // ---- rescale O accumulators by alpha
        #pragma unroll
        for (int nd = 0; nd < 8; ++nd)
            #pragma unroll
            for (int reg = 0; reg < 4; ++reg) o[nd][reg] *= alpha[reg];

        // wave-synchronous LDS ordering: drain ds_writes before cross-lane read
        __builtin_amdgcn_wave_barrier();
        __builtin_amdgcn_s_waitcnt(0xC07F);   // lgkmcnt(0), vm/exp unchanged
        __builtin_amdgcn_wave_barrier();

        // ---- P in A-layout: lane = query l15, k = key_local quad*8..+7
        bf16x8 a_p = *(const bf16x8*)(pw + l15 * PSTR + quad * 8);

        // ---- O += P @ V  (V fragments from transposed global Vt[d][s])
        const unsigned short* vrow = vbase + (size_t)l15 * S_LEN + j0 + quad * 8;
        #pragma unroll
        for (int nd = 0; nd < 8; ++nd) {
            bf16x8 b_v = *(const bf16x8*)(vrow + (size_t)nd * 16 * S_LEN);
            o[nd] = __builtin_amdgcn_mfma_f32_16x16x32_bf16(a_p, b_v, o[nd], 0, 0, 0);
        }
    }

    // ---- store partial (normalized O in bf16; m,l per row)
    #pragma unroll
    for (int reg = 0; reg < 4; ++reg) {
        int row = quad * 4 + reg;
        bool valid = m_s[reg] > -1e29f;
        float inv_l = valid ? 1.0f / l_s[reg] : 0.0f;
        if (l15 == 0) { m_lds[w][row] = m_s[reg]; l_lds[w][row] = l_s[reg]; }
        #pragma unroll
        for (int nd = 0; nd < 8; ++nd)
            O_lds[w][row * OSTR + nd * 16 + l15] = f2b(o[nd][reg] * inv_l);
    }
    __syncthreads();

    // ---- merge 4 partials -> ctx
    for (int e = threadIdx.x; e < 16 * HD; e += 256) {
        int q = e >> 7, d = e & 127;
        float mp[4], lp[4];
        float m = -1e30f;
        #pragma unroll
        for (int p = 0; p < 4; ++p) {
            mp[p] = m_lds[p][q]; lp[p] = l_lds[p][q];
            m = fmaxf(m, mp[p]);
        }
        float num = 0.f, den = 0.f;
        #pragma unroll
        for (int p = 0; p < 4; ++p) {
            float wgt = (mp[p] > -1e29f) ? __expf(mp[p] - m) * lp[p] : 0.f;
            num += wgt * b2f(O_lds[p][q * OSTR + d]);
            den += wgt;
        }
        Ctx[(size_t)(qb + q) * HIDDEN + h * HD + d] = f2b(num / den);
    }
}

// ---------------------------------------------------------------------------
extern "C" void kernel_launch(void* const* d_in, const int* in_sizes, int n_in,
                              void* d_out, int out_size, void* d_ws, size_t ws_size,
                              hipStream_t stream)
{
    const float* hidden = (const float*)d_in[0];
    const float* wq = (const float*)d_in[1];
    const float* wk = (const float*)d_in[2];
    const float* wv = (const float*)d_in[3];
    const float* wo = (const float*)d_in[4];
    const int* pos = (const int*)d_in[5];
    float* out = (float*)d_out;

    char* ws = (char*)d_ws;
    size_t off = 0;
    unsigned short* Hb  = (unsigned short*)(ws + off); off += (size_t)S_LEN * HIDDEN * 2;      // 8.4 MB
    unsigned short* Wqb = (unsigned short*)(ws + off); off += (size_t)HIDDEN * HIDDEN * 2;     // 2.1 MB
    unsigned short* Wkb = (unsigned short*)(ws + off); off += (size_t)NKV * HD * HIDDEN * 2;   // 0.5 MB
    unsigned short* Wvb = (unsigned short*)(ws + off); off += (size_t)NKV * HD * HIDDEN * 2;   // 0.5 MB
    unsigned short* Wob = (unsigned short*)(ws + off); off += (size_t)HIDDEN * HIDDEN * 2;     // 2.1 MB
    unsigned short* Qg  = (unsigned short*)(ws + off); off += (size_t)S_LEN * HIDDEN * 2;      // 8.4 MB
    unsigned short* Kg  = (unsigned short*)(ws + off); off += (size_t)S_LEN * NKV * HD * 2;    // 2.1 MB
    unsigned short* Vg  = (unsigned short*)(ws + off); off += (size_t)S_LEN * NKV * HD * 2;    // 2.1 MB
    unsigned short* Qb  = (unsigned short*)(ws + off); off += (size_t)S_LEN * HIDDEN * 2;      // 8.4 MB
    unsigned short* Kb  = (unsigned short*)(ws + off); off += (size_t)S_LEN * NKV * HD * 2;    // 2.1 MB
    unsigned short* Vt  = (unsigned short*)(ws + off); off += (size_t)S_LEN * NKV * HD * 2;    // 2.1 MB
    unsigned short* Cb  = (unsigned short*)(ws + off); off += (size_t)S_LEN * HIDDEN * 2;      // 8.4 MB
    // total ~47 MB

    // fp32 -> bf16 conversion of all inputs
    const int n_h  = S_LEN * HIDDEN / 4;
    const int n_wq = HIDDEN * HIDDEN / 4;
    const int n_wk = NKV * HD * HIDDEN / 4;
    const int n_wv = n_wk;
    const int n_wo = n_wq;
    int tot4 = n_h + n_wq + n_wk + n_wv + n_wo;
    cvt5<<<(tot4 + 255) / 256, 256, 0, stream>>>(
        hidden, Hb, n_h, wq, Wqb, n_wq, wk, Wkb, n_wk, wv, Wvb, n_wv, wo, Wob, n_wo);

    // Q/K/V projections (bf16 out)
    gemm32<<<(S_LEN / 32) * (HIDDEN / 64) / 4, 256, 0, stream>>>(
        Hb, Wqb, nullptr, Qg, S_LEN, HIDDEN, HIDDEN);
    gemm32<<<(S_LEN / 32) * ((NKV * HD) / 64) / 4, 256, 0, stream>>>(
        Hb, Wkb, nullptr, Kg, S_LEN, NKV * HD, HIDDEN);
    gemm32<<<(S_LEN / 32) * ((NKV * HD) / 64) / 4, 256, 0, stream>>>(
        Hb, Wvb, nullptr, Vg, S_LEN, NKV * HD, HIDDEN);

    // RoPE + V transpose
    rope_convert<<<S_LEN * 12 * 64 / 256, 256, 0, stream>>>(
        Qg, Kg, Vg, pos, Qb, Kb, Vt);

    // split-K flash attention
    attn_split<<<dim3(S_LEN / 16, NH), 256, 0, stream>>>(Qb, Kb, Vt, Cb);

    // output projection -> fp32 d_out
    gemm32<<<(S_LEN / 32) * (HIDDEN / 64) / 4, 256, 0, stream>>>(
        Cb, Wob, out, nullptr, S_LEN, HIDDEN, HIDDEN);
}